// Round 15
// baseline (622.063 us; speedup 1.0000x reference)
//
#include <hip/hip_runtime.h>
#include <cstdint>
#include <cstddef>
#include <type_traits>

#define NN   50000
#define NE   500000
#define DIN  64
#define EDIM 32
#define NH   4
#define NC   64
#define HC   256   // NH*NC
#define NGG  64
#define ND   64
#define LN_EPS 1e-5f
#define EESLOTS (NE + NN)   // edges + self-loops, CSR-slot order
#define SCAN_B   256
#define SCAN_NB  ((NN + SCAN_B - 1) / SCAN_B)   // 196

typedef __attribute__((ext_vector_type(4))) float f32x4;
typedef _Float16 f16;
typedef __attribute__((ext_vector_type(2))) _Float16 f16x2;
typedef __attribute__((ext_vector_type(4))) _Float16 f16x4;
typedef __attribute__((ext_vector_type(8))) _Float16 f16x8;

// ---------------------------------------------------------------------------
// CSR build: degree count -> 3-kernel device-wide scan -> fill
// ---------------------------------------------------------------------------
__global__ void count_deg(const int* __restrict__ dst, int* __restrict__ deg) {
    int e = blockIdx.x * blockDim.x + threadIdx.x;
    if (e < NE) atomicAdd(&deg[dst[e]], 1);
}

__global__ void scan_bsum(const int* __restrict__ deg, int* __restrict__ bsum) {
    __shared__ int s[SCAN_B];
    int t = threadIdx.x;
    int i = blockIdx.x * SCAN_B + t;
    s[t] = (i < NN) ? deg[i] : 0;
    __syncthreads();
    #pragma unroll
    for (int off = SCAN_B / 2; off > 0; off >>= 1) {
        if (t < off) s[t] += s[t + off];
        __syncthreads();
    }
    if (t == 0) bsum[blockIdx.x] = s[0];
}

__global__ void scan_boff(const int* __restrict__ bsum, int* __restrict__ boff) {
    __shared__ int s[SCAN_B];
    int t = threadIdx.x;
    int v = (t < SCAN_NB) ? bsum[t] : 0;
    s[t] = v;
    __syncthreads();
    #pragma unroll
    for (int off = 1; off < SCAN_B; off <<= 1) {
        int u = (t >= off) ? s[t - off] : 0;
        __syncthreads();
        s[t] += u;
        __syncthreads();
    }
    boff[t] = s[t] - v;   // exclusive
}

__global__ void scan_final(const int* __restrict__ deg, const int* __restrict__ boff,
                           int* __restrict__ row_ptr, int* __restrict__ cursor) {
    __shared__ int s[SCAN_B];
    int t = threadIdx.x;
    int i = blockIdx.x * SCAN_B + t;
    int v = (i < NN) ? deg[i] : 0;
    s[t] = v;
    __syncthreads();
    #pragma unroll
    for (int off = 1; off < SCAN_B; off <<= 1) {
        int u = (t >= off) ? s[t - off] : 0;
        __syncthreads();
        s[t] += u;
        __syncthreads();
    }
    int excl = boff[blockIdx.x] + s[t] - v;
    if (i < NN) {
        row_ptr[i] = excl;
        cursor[i] = excl;
    }
    if (i == 0) row_ptr[NN] = NE;
}

// fill_csr: writes directly into the slot arrays used downstream
// (srcf/dstf cover edge slots 0..NE; self slots appended by self_slots).
__global__ void fill_csr(const int* __restrict__ src, const int* __restrict__ dst,
                         int* __restrict__ cursor, int* __restrict__ srcf,
                         int* __restrict__ dstf, int* __restrict__ csr_eid) {
    int e = blockIdx.x * blockDim.x + threadIdx.x;
    if (e < NE) {
        int d = dst[e];
        int pos = atomicAdd(&cursor[d], 1);
        srcf[pos] = src[e];
        dstf[pos] = d;
        csr_eid[pos] = e;
    }
}

// ---------------------------------------------------------------------------
// perm_ef: materialize ef in CSR-slot order as f16.
// ---------------------------------------------------------------------------
__global__ void perm_ef(const float* __restrict__ ef, const int* __restrict__ csr_eid,
                        f16* __restrict__ efp) {
    int idx = blockIdx.x * blockDim.x + threadIdx.x;
    if (idx >= NE * 4) return;
    int j = idx >> 2, ch = idx & 3;
    int eid = csr_eid[j];
    const float* sp = ef + (size_t)eid * EDIM + ch * 8;
    float4 v0 = *(const float4*)sp;
    float4 v1 = *(const float4*)(sp + 4);
    f16x8 o;
    o[0] = (f16)v0.x; o[1] = (f16)v0.y; o[2] = (f16)v0.z; o[3] = (f16)v0.w;
    o[4] = (f16)v1.x; o[5] = (f16)v1.y; o[6] = (f16)v1.z; o[7] = (f16)v1.w;
    *(f16x8*)(efp + (size_t)j * EDIM + ch * 8) = o;
}

// ---------------------------------------------------------------------------
// self_slots: per-node mean of incident edge attrs -> self-loop slots of efp.
// ---------------------------------------------------------------------------
__global__ void self_slots(const int* __restrict__ row_ptr,
                           f16* __restrict__ efp,
                           int* __restrict__ srcf, int* __restrict__ dstf) {
    int idx = blockIdx.x * blockDim.x + threadIdx.x;
    if (idx >= NN * EDIM) return;
    int n = idx >> 5, c = idx & 31;
    int s = row_ptr[n], e = row_ptr[n + 1];
    float acc = 0.f;
    for (int j = s; j < e; j++)
        acc += (float)efp[(size_t)j * EDIM + c];
    float m = acc / (float)max(e - s, 1);
    efp[(size_t)(NE + n) * EDIM + c] = (f16)m;
    if (c == 0) { srcf[NE + n] = n; dstf[NE + n] = n; }
}

// ---------------------------------------------------------------------------
// Weight pre-passes
// ---------------------------------------------------------------------------
// W[K][N] fp32 -> transposed f16 [N][K]
__global__ void conv_wtf(const float* __restrict__ W, f16* __restrict__ o, int K, int Nn) {
    int idx = blockIdx.x * blockDim.x + threadIdx.x;
    if (idx >= K * Nn) return;
    int k = idx / Nn, n = idx - k * Nn;
    o[(size_t)n * K + k] = (f16)W[idx];
}

// We[EDIM][HC] fp32 -> PERMUTED transposed f16 [HC][EDIM].
__global__ void conv_wet(const float* __restrict__ We, f16* __restrict__ wet) {
    int idx = blockIdx.x * blockDim.x + threadIdx.x;
    if (idx >= EDIM * HC) return;
    int k = idx / HC, c = idx - k * HC;
    int r = ((c & 15) << 4) | (c >> 4);   // inverse of c = (r&15)*16 + (r>>4)
    wet[(size_t)r * EDIM + k] = (f16)We[idx];
}

__global__ void concat_bias(const float* __restrict__ a, const float* __restrict__ b,
                            float* __restrict__ o) {
    int i = threadIdx.x;
    o[i] = a[i];
    o[i + HC] = b[i];
}

#define LDT 40

// ---------------------------------------------------------------------------
// Wide fused GEMM (f16 single-term): [xl|xr] = A[M,K] @ [Wl|Wr] + [bl|br].
// Tile 64x256 (grid-x = 2): halves the A re-read vs 64x128 (each row-block
// loads A once per column-block). Block 0 -> xl entirely, block 1 -> xr.
// acc[16] (~64 VGPR) at natural occupancy — no forced launch bounds.
// ---------------------------------------------------------------------------
template <typename TA>
__global__ __launch_bounds__(256, 2)
void gemm_wide(const TA* __restrict__ A, const f16* __restrict__ Bt,
               const float* __restrict__ bias,
               f16* __restrict__ xlb, f16* __restrict__ xrb, int M, int K) {
    __shared__ _Float16 Af[64][LDT];
    __shared__ _Float16 Bf[256][LDT];
    int tid = threadIdx.x;
    int lane = tid & 63, w = tid >> 6;
    int m = lane & 15, q = lane >> 4;
    int rowBase = blockIdx.y * 64, colBase = blockIdx.x * 256;
    f32x4 acc[16];
    #pragma unroll
    for (int ct = 0; ct < 16; ct++) acc[ct] = (f32x4){0.f, 0.f, 0.f, 0.f};

    for (int kk = 0; kk < K; kk += 32) {
        // ---- stage A: 64 rows x 32 k -> f16 LDS (2 chunks of 4 / thread)
        #pragma unroll
        for (int u = 0; u < 2; u++) {
            int f = tid + 256 * u;
            int r = f >> 3;
            int k4 = (f & 7) * 4;
            int row = rowBase + r;
            f16x4 h = (f16x4){(f16)0, (f16)0, (f16)0, (f16)0};
            if (row < M) {
                if constexpr (std::is_same_v<TA, float>) {
                    float4 v = *(const float4*)(A + (size_t)row * K + kk + k4);
                    h[0] = (f16)v.x; h[1] = (f16)v.y; h[2] = (f16)v.z; h[3] = (f16)v.w;
                } else {
                    h = *(const f16x4*)(A + (size_t)row * K + kk + k4);
                }
            }
            *(f16x4*)&Af[r][k4] = h;
        }
        // ---- stage B: 256 rows x 32 k f16 (2 f16x8 / thread)
        {
            size_t goff = (size_t)(colBase + tid) * K + kk;
            *(f16x8*)&Bf[tid][0] = *(const f16x8*)(Bt + goff);
            *(f16x8*)&Bf[tid][8] = *(const f16x8*)(Bt + goff + 8);
            *(f16x8*)&Bf[tid][16] = *(const f16x8*)(Bt + goff + 16);
            *(f16x8*)&Bf[tid][24] = *(const f16x8*)(Bt + goff + 24);
        }
        __syncthreads();
        f16x8 a = *(const f16x8*)&Af[w * 16 + m][q * 8];
        #pragma unroll
        for (int ct = 0; ct < 16; ct++) {
            f16x8 b = *(const f16x8*)&Bf[ct * 16 + m][q * 8];
            acc[ct] = __builtin_amdgcn_mfma_f32_16x16x32_f16(a, b, acc[ct], 0, 0, 0);
        }
        __syncthreads();
    }
    f16* ob = (colBase < HC) ? xlb : xrb;
    int obase = (colBase < HC) ? colBase : colBase - HC;
    #pragma unroll
    for (int ct = 0; ct < 16; ct++) {
        int col = colBase + ct * 16 + m;
        int ocol = obase + ct * 16 + m;
        float bb = bias[col];
        #pragma unroll
        for (int r = 0; r < 4; r++) {
            int row = rowBase + w * 16 + q * 4 + r;
            if (row < M) ob[(size_t)row * HC + ocol] = (f16)(acc[ct][r] + bb);
        }
    }
}

// ---------------------------------------------------------------------------
// Head GEMM (64x64, f16 single-term) with fused LayerNorm epilogue.
// ---------------------------------------------------------------------------
__global__ __launch_bounds__(256, 2)
void gemm_head(const f16* __restrict__ A, const f16* __restrict__ Bt,
               const float* __restrict__ bias,
               float* __restrict__ C, int M, int K,
               const float* __restrict__ ln_g, const float* __restrict__ ln_b) {
    __shared__ _Float16 Af[64][LDT];
    __shared__ _Float16 Bf[64][LDT];
    int tid = threadIdx.x;
    int lane = tid & 63, w = tid >> 6;
    int m = lane & 15, q = lane >> 4;
    int rowBase = blockIdx.y * 64;
    f32x4 acc[4];
    #pragma unroll
    for (int ct = 0; ct < 4; ct++) acc[ct] = (f32x4){0.f, 0.f, 0.f, 0.f};

    for (int kk = 0; kk < K; kk += 32) {
        #pragma unroll
        for (int u = 0; u < 2; u++) {
            int f = tid + 256 * u;
            int r = f >> 3;
            int k4 = (f & 7) * 4;
            int row = rowBase + r;
            f16x4 h = (f16x4){(f16)0, (f16)0, (f16)0, (f16)0};
            if (row < M) h = *(const f16x4*)(A + (size_t)row * K + kk + k4);
            *(f16x4*)&Af[r][k4] = h;
        }
        {
            int n = tid >> 2;
            int ch = tid & 3;
            size_t goff = (size_t)n * K + kk + ch * 8;
            *(f16x8*)&Bf[n][ch * 8] = *(const f16x8*)(Bt + goff);
        }
        __syncthreads();
        f16x8 a = *(const f16x8*)&Af[w * 16 + m][q * 8];
        #pragma unroll
        for (int ct = 0; ct < 4; ct++) {
            f16x8 b = *(const f16x8*)&Bf[ct * 16 + m][q * 8];
            acc[ct] = __builtin_amdgcn_mfma_f32_16x16x32_f16(a, b, acc[ct], 0, 0, 0);
        }
        __syncthreads();
    }
    // LN epilogue: row held by 16 lanes (m) x 4 cols (ct)
    #pragma unroll
    for (int r = 0; r < 4; r++) {
        float v[4];
        float sum = 0.f;
        #pragma unroll
        for (int ct = 0; ct < 4; ct++) {
            v[ct] = acc[ct][r] + bias[ct * 16 + m];
            sum += v[ct];
        }
        sum += __shfl_xor(sum, 1); sum += __shfl_xor(sum, 2);
        sum += __shfl_xor(sum, 4); sum += __shfl_xor(sum, 8);
        float mu = sum * (1.f / 64.f);
        float sq = 0.f;
        #pragma unroll
        for (int ct = 0; ct < 4; ct++) {
            float d = v[ct] - mu;
            sq += d * d;
        }
        sq += __shfl_xor(sq, 1); sq += __shfl_xor(sq, 2);
        sq += __shfl_xor(sq, 4); sq += __shfl_xor(sq, 8);
        float inv = rsqrtf(sq * (1.f / 64.f) + LN_EPS);
        int row = rowBase + w * 16 + q * 4 + r;
        if (row < M) {
            #pragma unroll
            for (int ct = 0; ct < 4; ct++) {
                int col = ct * 16 + m;
                C[(size_t)row * 64 + col] = (v[ct] - mu) * inv * ln_g[col] + ln_b[col];
            }
        }
    }
}

// ---------------------------------------------------------------------------
// score_kernel (persistent): per 64-slot group, ee = ea @ We via single f16
// MFMA, fused GATv2 score epilogue in packed f16 (R10 known-good form).
// Lane m owns channels [m*16 .. m*16+15].
// ---------------------------------------------------------------------------
__global__ __launch_bounds__(256, 2)
void score_kernel(const f16* __restrict__ efp,
                  const int* __restrict__ srcf, const int* __restrict__ dstf,
                  const f16* __restrict__ xlb, const f16* __restrict__ xrb,
                  const f16* __restrict__ wet,
                  const float* __restrict__ att, float* __restrict__ alpha) {
    __shared__ _Float16 Af[64][LDT];
    __shared__ _Float16 Bf[256][LDT];
    __shared__ int s_src[64], s_dst[64];
    int tid = threadIdx.x;
    int lane = tid & 63, w = tid >> 6;
    int m = lane & 15, q = lane >> 4;

    // stage B (We^T permuted f16, [256][32]) ONCE
    #pragma unroll
    for (int u = 0; u < 4; u++) {
        *(f16x8*)&Bf[tid][u * 8] = *(const f16x8*)(wet + (size_t)tid * EDIM + u * 8);
    }
    // att coefficients of channels m*16..m*16+15 as packed f16
    f16x8 attp0, attp1;
    #pragma unroll
    for (int i = 0; i < 8; i++) {
        attp0[i] = (f16)att[m * 16 + i];
        attp1[i] = (f16)att[m * 16 + 8 + i];
    }

    const f16x8 zero8 = {(f16)0, (f16)0, (f16)0, (f16)0, (f16)0, (f16)0, (f16)0, (f16)0};

    int groups = (EESLOTS + 63) >> 6;
    for (int g = blockIdx.x; g < groups; g += gridDim.x) {
        int base = g << 6;
        __syncthreads();   // protect Af + s_src reads of previous group
        // stage A: 64 slots x 32 k, sequential f16 stream from efp
        {
            int r = tid >> 2, ch = tid & 3;
            int j = base + r;
            if (j >= EESLOTS) j = EESLOTS - 1;
            *(f16x8*)&Af[r][ch * 8] = *(const f16x8*)(efp + (size_t)j * EDIM + ch * 8);
            if (ch == 0) { s_src[r] = srcf[j]; s_dst[r] = dstf[j]; }
        }
        __syncthreads();

        f16x8 a = *(const f16x8*)&Af[w * 16 + m][q * 8];
        f32x4 acc[16];
        #pragma unroll
        for (int ct = 0; ct < 16; ct++) {
            f16x8 b = *(const f16x8*)&Bf[ct * 16 + m][q * 8];
            acc[ct] = __builtin_amdgcn_mfma_f32_16x16x32_f16(
                a, b, (f32x4){0.f, 0.f, 0.f, 0.f}, 0, 0, 0);
        }

        // epilogue: per-slot score (packed f16 math)
        #pragma unroll
        for (int r = 0; r < 4; r++) {
            int sl = w * 16 + q * 4 + r;
            int slot = base + sl;
            int ss = s_src[sl], dd = s_dst[sl];
            const f16* xlp = xlb + (size_t)ss * HC + m * 16;
            const f16* xrp = xrb + (size_t)dd * HC + m * 16;
            f16x8 xa0 = *(const f16x8*)(xlp);
            f16x8 xa1 = *(const f16x8*)(xlp + 8);
            f16x8 xb0 = *(const f16x8*)(xrp);
            f16x8 xb1 = *(const f16x8*)(xrp + 8);
            f16x8 z0 = xa0 + xb0;
            f16x8 z1 = xa1 + xb1;
            f16x8 e0, e1;
            #pragma unroll
            for (int i = 0; i < 8; i++) {
                e0[i] = (f16)acc[i][r];
                e1[i] = (f16)acc[8 + i][r];
            }
            z0 += e0;
            z1 += e1;
            f16x8 lz0 = __builtin_elementwise_min(z0, zero8) * (f16)0.2f
                      + __builtin_elementwise_max(z0, zero8);
            f16x8 lz1 = __builtin_elementwise_min(z1, zero8) * (f16)0.2f
                      + __builtin_elementwise_max(z1, zero8);
            float s0 = 0.f, s1 = 0.f;
#if __has_builtin(__builtin_amdgcn_fdot2)
            #pragma unroll
            for (int i = 0; i < 4; i++) {
                f16x2 a2 = {lz0[2 * i], lz0[2 * i + 1]};
                f16x2 b2 = {attp0[2 * i], attp0[2 * i + 1]};
                s0 = __builtin_amdgcn_fdot2(a2, b2, s0, false);
                f16x2 c2 = {lz1[2 * i], lz1[2 * i + 1]};
                f16x2 d2 = {attp1[2 * i], attp1[2 * i + 1]};
                s1 = __builtin_amdgcn_fdot2(c2, d2, s1, false);
            }
#else
            #pragma unroll
            for (int i = 0; i < 8; i++) {
                s0 += (float)lz0[i] * (float)attp0[i];
                s1 += (float)lz1[i] * (float)attp1[i];
            }
#endif
            float s = s0 + s1;
            // head h = m>>2: reduce over the 4 lanes m in [4h..4h+3]
            s += __shfl_xor(s, 1);
            s += __shfl_xor(s, 2);
            if ((m & 3) == 0 && slot < EESLOTS) {
                alpha[(size_t)slot * 4 + (m >> 2)] = s;
            }
        }
    }
}

// ---------------------------------------------------------------------------
// Lean aggregation: softmax over precomputed alpha (shift = alpha_self),
// weighted gather of fp16 xl from xlb. One wave per node, ILP x8.
// Output xb in FP16.
// ---------------------------------------------------------------------------
__global__ __launch_bounds__(256)
void gat_aggr(const f16* __restrict__ xlb, const float* __restrict__ alpha,
              const int* __restrict__ row_ptr, const int* __restrict__ srcf,
              const float* __restrict__ bias, f16* __restrict__ out, int do_relu) {
    int lane = threadIdx.x & 63;
    int wv = threadIdx.x >> 6;
    int n = blockIdx.x * 4 + wv;
    if (n >= NN) return;
    int h = lane >> 4;
    float4 bb = *(const float4*)(bias + 4 * lane);
    int s0 = row_ptr[n], e0 = row_ptr[n + 1];
    float aself = alpha[(size_t)(NE + n) * 4 + h];
    float denom = 1.f;
    f16x4 xs = *(const f16x4*)(xlb + (size_t)n * HC + 4 * lane);
    float4 acc = make_float4((float)xs[0], (float)xs[1], (float)xs[2], (float)xs[3]);

    for (int j0 = s0; j0 < e0; j0 += 64) {
        int cnt = min(64, e0 - j0);
        int sidx = (j0 + lane < e0) ? srcf[j0 + lane] : 0;
        int t = 0;
        for (; t + 7 < cnt; t += 8) {
            int si[8];
            #pragma unroll
            for (int u = 0; u < 8; u++) si[u] = __shfl(sidx, t + u);
            float av[8];
            #pragma unroll
            for (int u = 0; u < 8; u++)
                av[u] = __expf(alpha[(size_t)(j0 + t + u) * 4 + h] - aself);
            f16x4 xv[8];
            #pragma unroll
            for (int u = 0; u < 8; u++)
                xv[u] = *(const f16x4*)(xlb + (size_t)si[u] * HC + 4 * lane);
            #pragma unroll
            for (int u = 0; u < 8; u++) {
                denom += av[u];
                acc.x += av[u] * (float)xv[u][0];
                acc.y += av[u] * (float)xv[u][1];
                acc.z += av[u] * (float)xv[u][2];
                acc.w += av[u] * (float)xv[u][3];
            }
        }
        for (; t < cnt; t++) {
            int sa = __shfl(sidx, t);
            float a0 = __expf(alpha[(size_t)(j0 + t) * 4 + h] - aself);
            f16x4 x0 = *(const f16x4*)(xlb + (size_t)sa * HC + 4 * lane);
            denom += a0;
            acc.x += a0 * (float)x0[0]; acc.y += a0 * (float)x0[1];
            acc.z += a0 * (float)x0[2]; acc.w += a0 * (float)x0[3];
        }
    }

    float inv = 1.f / denom;
    float rx = acc.x * inv + bb.x;
    float ry = acc.y * inv + bb.y;
    float rz = acc.z * inv + bb.z;
    float rw = acc.w * inv + bb.w;
    if (do_relu) {
        rx = fmaxf(rx, 0.f); ry = fmaxf(ry, 0.f);
        rz = fmaxf(rz, 0.f); rw = fmaxf(rw, 0.f);
    }
    f16x4 o;
    o[0] = (f16)rx; o[1] = (f16)ry; o[2] = (f16)rz; o[3] = (f16)rw;
    *(f16x4*)(out + (size_t)n * HC + 4 * lane) = o;
}

// ---------------------------------------------------------------------------
// Graph mean pre-reduction exploiting sorted batch. 64 rows/block, f16 input.
// ---------------------------------------------------------------------------
__global__ void graph_sum(const f16* __restrict__ x, const int* __restrict__ batch,
                          float* __restrict__ gsum, float* __restrict__ gcnt) {
    int c = threadIdx.x;
    int r0 = blockIdx.x * 64;
    int r1 = min(r0 + 64, NN);
    if (r0 >= NN) return;
    float acc = 0.f;
    int gcur = batch[r0];
    for (int n = r0; n < r1; n++) {
        int g = batch[n];
        if (g != gcur) {
            atomicAdd(&gsum[(size_t)gcur * HC + c], acc);
            acc = 0.f; gcur = g;
        }
        acc += (float)x[(size_t)n * HC + c];
    }
    atomicAdd(&gsum[(size_t)gcur * HC + c], acc);
    if (c == 0) {
        int cnt = 0; gcur = batch[r0];
        for (int n = r0; n < r1; n++) {
            int g = batch[n];
            if (g != gcur) {
                atomicAdd(&gcnt[gcur], (float)cnt);
                cnt = 0; gcur = g;
            }
            cnt++;
        }
        atomicAdd(&gcnt[gcur], (float)cnt);
    }
}

__global__ void glob_kernel(const float* __restrict__ gsum, const float* __restrict__ gcnt,
                            const float* __restrict__ W, const float* __restrict__ bias,
                            const float* __restrict__ g, const float* __restrict__ b,
                            float* __restrict__ out) {
    int gi = blockIdx.x;
    int lane = threadIdx.x;
    float inv = 1.f / fmaxf(gcnt[gi], 1.f);
    float acc = 0.f;
    for (int k = 0; k < HC; k++)
        acc += (gsum[(size_t)gi * HC + k] * inv) * W[(size_t)k * ND + lane];
    acc += bias[lane];
    float s = acc;
    #pragma unroll
    for (int o = 32; o >= 1; o >>= 1) s += __shfl_xor(s, o);
    float mu = s * (1.f / 64.f);
    float dv = acc - mu;
    float q = dv * dv;
    #pragma unroll
    for (int o = 32; o >= 1; o >>= 1) q += __shfl_xor(q, o);
    float var = q * (1.f / 64.f);
    out[(size_t)gi * ND + lane] = dv * rsqrtf(var + LN_EPS) * g[lane] + b[lane];
}

// ---------------------------------------------------------------------------
extern "C" void kernel_launch(void* const* d_in, const int* in_sizes, int n_in,
                              void* d_out, int out_size, void* d_ws, size_t ws_size,
                              hipStream_t stream) {
    (void)in_sizes; (void)n_in; (void)out_size; (void)ws_size;
    const float* node_feature = (const float*)d_in[0];
    const int*   edge_index   = (const int*)d_in[1];
    const float* edge_feature = (const float*)d_in[2];
    const int*   batch        = (const int*)d_in[3];
    const float* Wl0   = (const float*)d_in[4];
    const float* bl0   = (const float*)d_in[5];
    const float* Wr0   = (const float*)d_in[6];
    const float* br0   = (const float*)d_in[7];
    const float* We0   = (const float*)d_in[8];
    const float* att0  = (const float*)d_in[9];
    const float* bias0 = (const float*)d_in[10];
    const float* Wl1   = (const float*)d_in[11];
    const float* bl1   = (const float*)d_in[12];
    const float* Wr1   = (const float*)d_in[13];
    const float* br1   = (const float*)d_in[14];
    const float* We1   = (const float*)d_in[15];
    const float* att1  = (const float*)d_in[16];
    const float* bias1 = (const float*)d_in[17];
    const float* node_W  = (const float*)d_in[18];
    const float* node_b  = (const float*)d_in[19];
    const float* graph_W = (const float*)d_in[20];
    const float* graph_b = (const float*)d_in[21];
    const float* nn_g = (const float*)d_in[22];
    const float* nn_b = (const float*)d_in[23];
    const float* gn_g = (const float*)d_in[24];
    const float* gn_b = (const float*)d_in[25];

    const int* src = edge_index;
    const int* dst = edge_index + NE;

    char* p = (char*)d_ws;
    auto carve = [&](size_t bytes) {
        char* r = p;
        p += (bytes + 255) & ~(size_t)255;
        return r;
    };
    int*   row_ptr   = (int*)carve((NN + 1) * sizeof(int));
    int*   cursor    = (int*)carve(NN * sizeof(int));
    int*   deg       = (int*)carve(NN * sizeof(int));
    int*   bsum      = (int*)carve(SCAN_B * sizeof(int));
    int*   boff      = (int*)carve(SCAN_B * sizeof(int));
    int*   csr_eid   = (int*)carve((size_t)NE * sizeof(int));
    int*   srcf      = (int*)carve((size_t)EESLOTS * sizeof(int));
    int*   dstf      = (int*)carve((size_t)EESLOTS * sizeof(int));
    f16*   efp       = (f16*)carve((size_t)EESLOTS * EDIM * sizeof(f16));
    f16*   xlb       = (f16*)carve((size_t)NN * HC * sizeof(f16));   // xl fp16
    f16*   xrb       = (f16*)carve((size_t)NN * HC * sizeof(f16));   // xr fp16
    f16*   xb        = (f16*)carve((size_t)NN * HC * sizeof(f16));   // fp16 node state
    float* alpha     = (float*)carve((size_t)EESLOTS * NH * sizeof(float));
    float* gsum      = (float*)carve((size_t)(NGG * HC + NGG) * sizeof(float));
    float* gcnt      = gsum + (size_t)NGG * HC;
    // layer GEMM weights: f16 transposed [512][K]
    f16* wlr0f = (f16*)carve((size_t)(2 * HC) * DIN * sizeof(f16));
    f16* wlr1f = (f16*)carve((size_t)(2 * HC) * HC * sizeof(f16));
    // head weights: f16 transposed [ND][HC]
    f16* nwf = (f16*)carve((size_t)ND * HC * sizeof(f16));
    f16* wet0 = (f16*)carve((size_t)EDIM * HC * sizeof(f16));
    f16* wet1 = (f16*)carve((size_t)EDIM * HC * sizeof(f16));
    float* b0cat = (float*)carve(2 * HC * sizeof(float));
    float* b1cat = (float*)carve(2 * HC * sizeof(float));

    hipMemsetAsync(deg, 0, NN * sizeof(int), stream);
    hipMemsetAsync(gsum, 0, (NGG * HC + NGG) * sizeof(float), stream);

    // CSR (3-kernel scan) + efp pre-permutation + weight conversion
    count_deg<<<(NE + 255) / 256, 256, 0, stream>>>(dst, deg);
    scan_bsum<<<SCAN_NB, SCAN_B, 0, stream>>>(deg, bsum);
    scan_boff<<<1, SCAN_B, 0, stream>>>(bsum, boff);
    scan_final<<<SCAN_NB, SCAN_B, 0, stream>>>(deg, boff, row_ptr, cursor);
    fill_csr<<<(NE + 255) / 256, 256, 0, stream>>>(src, dst, cursor, srcf, dstf, csr_eid);
    perm_ef<<<(NE * 4 + 255) / 256, 256, 0, stream>>>(edge_feature, csr_eid, efp);
    self_slots<<<(NN * EDIM + 255) / 256, 256, 0, stream>>>(row_ptr, efp, srcf, dstf);
    conv_wtf<<<(DIN * HC + 255) / 256, 256, 0, stream>>>(Wl0, wlr0f, DIN, HC);
    conv_wtf<<<(DIN * HC + 255) / 256, 256, 0, stream>>>(Wr0, wlr0f + (size_t)HC * DIN, DIN, HC);
    conv_wtf<<<(HC * HC + 255) / 256, 256, 0, stream>>>(Wl1, wlr1f, HC, HC);
    conv_wtf<<<(HC * HC + 255) / 256, 256, 0, stream>>>(Wr1, wlr1f + (size_t)HC * HC, HC, HC);
    conv_wtf<<<(HC * ND + 255) / 256, 256, 0, stream>>>(node_W, nwf, HC, ND);
    conv_wet<<<(EDIM * HC + 255) / 256, 256, 0, stream>>>(We0, wet0);
    conv_wet<<<(EDIM * HC + 255) / 256, 256, 0, stream>>>(We1, wet1);
    concat_bias<<<1, 256, 0, stream>>>(bl0, br0, b0cat);
    concat_bias<<<1, 256, 0, stream>>>(bl1, br1, b1cat);

    dim3 gw(2, (NN + 63) / 64);
    // Layer 0
    gemm_wide<float><<<gw, 256, 0, stream>>>(node_feature, wlr0f, b0cat, xlb, xrb, NN, DIN);
    score_kernel<<<2048, 256, 0, stream>>>(efp, srcf, dstf, xlb, xrb, wet0, att0, alpha);
    gat_aggr<<<(NN + 3) / 4, 256, 0, stream>>>(xlb, alpha, row_ptr, srcf, bias0, xb, 1);
    // Layer 1
    gemm_wide<f16><<<gw, 256, 0, stream>>>(xb, wlr1f, b1cat, xlb, xrb, NN, HC);
    score_kernel<<<2048, 256, 0, stream>>>(efp, srcf, dstf, xlb, xrb, wet1, att1, alpha);
    gat_aggr<<<(NN + 3) / 4, 256, 0, stream>>>(xlb, alpha, row_ptr, srcf, bias1, xb, 0);

    // Heads
    float* out_local = (float*)d_out;
    float* out_glob  = out_local + (size_t)NN * ND;
    dim3 gh(1, (NN + 63) / 64);
    gemm_head<<<gh, 256, 0, stream>>>(xb, nwf, node_b, out_local, NN, HC, nn_g, nn_b);
    graph_sum<<<(NN + 63) / 64, 256, 0, stream>>>(xb, batch, gsum, gcnt);
    glob_kernel<<<NGG, 64, 0, stream>>>(gsum, gcnt, graph_W, graph_b, gn_g, gn_b, out_glob);
}

// Round 16
// 595.456 us; speedup vs baseline: 1.0447x; 1.0447x over previous
//
#include <hip/hip_runtime.h>
#include <cstdint>
#include <cstddef>
#include <type_traits>

#define NN   50000
#define NE   500000
#define DIN  64
#define EDIM 32
#define NH   4
#define NC   64
#define HC   256   // NH*NC
#define NGG  64
#define ND   64
#define LN_EPS 1e-5f
#define EESLOTS (NE + NN)   // edges + self-loops, CSR-slot order
#define SCAN_B   256
#define SCAN_NB  ((NN + SCAN_B - 1) / SCAN_B)   // 196

typedef __attribute__((ext_vector_type(4))) float f32x4;
typedef _Float16 f16;
typedef __attribute__((ext_vector_type(2))) _Float16 f16x2;
typedef __attribute__((ext_vector_type(4))) _Float16 f16x4;
typedef __attribute__((ext_vector_type(8))) _Float16 f16x8;

// ---------------------------------------------------------------------------
// CSR build: degree count -> 3-kernel device-wide scan -> fill
// ---------------------------------------------------------------------------
__global__ void count_deg(const int* __restrict__ dst, int* __restrict__ deg) {
    int e = blockIdx.x * blockDim.x + threadIdx.x;
    if (e < NE) atomicAdd(&deg[dst[e]], 1);
}

__global__ void scan_bsum(const int* __restrict__ deg, int* __restrict__ bsum) {
    __shared__ int s[SCAN_B];
    int t = threadIdx.x;
    int i = blockIdx.x * SCAN_B + t;
    s[t] = (i < NN) ? deg[i] : 0;
    __syncthreads();
    #pragma unroll
    for (int off = SCAN_B / 2; off > 0; off >>= 1) {
        if (t < off) s[t] += s[t + off];
        __syncthreads();
    }
    if (t == 0) bsum[blockIdx.x] = s[0];
}

__global__ void scan_boff(const int* __restrict__ bsum, int* __restrict__ boff) {
    __shared__ int s[SCAN_B];
    int t = threadIdx.x;
    int v = (t < SCAN_NB) ? bsum[t] : 0;
    s[t] = v;
    __syncthreads();
    #pragma unroll
    for (int off = 1; off < SCAN_B; off <<= 1) {
        int u = (t >= off) ? s[t - off] : 0;
        __syncthreads();
        s[t] += u;
        __syncthreads();
    }
    boff[t] = s[t] - v;   // exclusive
}

__global__ void scan_final(const int* __restrict__ deg, const int* __restrict__ boff,
                           int* __restrict__ row_ptr, int* __restrict__ cursor) {
    __shared__ int s[SCAN_B];
    int t = threadIdx.x;
    int i = blockIdx.x * SCAN_B + t;
    int v = (i < NN) ? deg[i] : 0;
    s[t] = v;
    __syncthreads();
    #pragma unroll
    for (int off = 1; off < SCAN_B; off <<= 1) {
        int u = (t >= off) ? s[t - off] : 0;
        __syncthreads();
        s[t] += u;
        __syncthreads();
    }
    int excl = boff[blockIdx.x] + s[t] - v;
    if (i < NN) {
        row_ptr[i] = excl;
        cursor[i] = excl;
    }
    if (i == 0) row_ptr[NN] = NE;
}

// fill_csr: writes directly into the slot arrays used downstream.
__global__ void fill_csr(const int* __restrict__ src, const int* __restrict__ dst,
                         int* __restrict__ cursor, int* __restrict__ srcf,
                         int* __restrict__ dstf, int* __restrict__ csr_eid) {
    int e = blockIdx.x * blockDim.x + threadIdx.x;
    if (e < NE) {
        int d = dst[e];
        int pos = atomicAdd(&cursor[d], 1);
        srcf[pos] = src[e];
        dstf[pos] = d;
        csr_eid[pos] = e;
    }
}

// ---------------------------------------------------------------------------
// perm_ef: materialize ef in CSR-slot order as f16.
// ---------------------------------------------------------------------------
__global__ void perm_ef(const float* __restrict__ ef, const int* __restrict__ csr_eid,
                        f16* __restrict__ efp) {
    int idx = blockIdx.x * blockDim.x + threadIdx.x;
    if (idx >= NE * 4) return;
    int j = idx >> 2, ch = idx & 3;
    int eid = csr_eid[j];
    const float* sp = ef + (size_t)eid * EDIM + ch * 8;
    float4 v0 = *(const float4*)sp;
    float4 v1 = *(const float4*)(sp + 4);
    f16x8 o;
    o[0] = (f16)v0.x; o[1] = (f16)v0.y; o[2] = (f16)v0.z; o[3] = (f16)v0.w;
    o[4] = (f16)v1.x; o[5] = (f16)v1.y; o[6] = (f16)v1.z; o[7] = (f16)v1.w;
    *(f16x8*)(efp + (size_t)j * EDIM + ch * 8) = o;
}

// ---------------------------------------------------------------------------
// self_slots: per-node mean of incident edge attrs -> self-loop slots of efp.
// ---------------------------------------------------------------------------
__global__ void self_slots(const int* __restrict__ row_ptr,
                           f16* __restrict__ efp,
                           int* __restrict__ srcf, int* __restrict__ dstf) {
    int idx = blockIdx.x * blockDim.x + threadIdx.x;
    if (idx >= NN * EDIM) return;
    int n = idx >> 5, c = idx & 31;
    int s = row_ptr[n], e = row_ptr[n + 1];
    float acc = 0.f;
    for (int j = s; j < e; j++)
        acc += (float)efp[(size_t)j * EDIM + c];
    float m = acc / (float)max(e - s, 1);
    efp[(size_t)(NE + n) * EDIM + c] = (f16)m;
    if (c == 0) { srcf[NE + n] = n; dstf[NE + n] = n; }
}

// ---------------------------------------------------------------------------
// Weight pre-passes
// ---------------------------------------------------------------------------
// W[K][N] fp32 -> transposed f16 [N][K]
__global__ void conv_wtf(const float* __restrict__ W, f16* __restrict__ o, int K, int Nn) {
    int idx = blockIdx.x * blockDim.x + threadIdx.x;
    if (idx >= K * Nn) return;
    int k = idx / Nn, n = idx - k * Nn;
    o[(size_t)n * K + k] = (f16)W[idx];
}

// We[EDIM][HC] fp32 -> PERMUTED transposed f16 [HC][EDIM].
__global__ void conv_wet(const float* __restrict__ We, f16* __restrict__ wet) {
    int idx = blockIdx.x * blockDim.x + threadIdx.x;
    if (idx >= EDIM * HC) return;
    int k = idx / HC, c = idx - k * HC;
    int r = ((c & 15) << 4) | (c >> 4);   // inverse of c = (r&15)*16 + (r>>4)
    wet[(size_t)r * EDIM + k] = (f16)We[idx];
}

__global__ void concat_bias(const float* __restrict__ a, const float* __restrict__ b,
                            float* __restrict__ o) {
    int i = threadIdx.x;
    o[i] = a[i];
    o[i + HC] = b[i];
}

#define LDT 40

// ---------------------------------------------------------------------------
// Wide fused GEMM (f16 single-term): [xl|xr] = A[M,K] @ [Wl|Wr] + [bl|br].
// Tile 64x128, grid-x = 4 (R14 known-good shape: the 64x256 variant
// regressed on LDS-write conflicts / lost latency hiding).
// ---------------------------------------------------------------------------
template <typename TA>
__global__ __launch_bounds__(256, 2)
void gemm_wide(const TA* __restrict__ A, const f16* __restrict__ Bt,
               const float* __restrict__ bias,
               f16* __restrict__ xlb, f16* __restrict__ xrb, int M, int K) {
    __shared__ _Float16 Af[64][LDT];
    __shared__ _Float16 Bf[128][LDT];
    int tid = threadIdx.x;
    int lane = tid & 63, w = tid >> 6;
    int m = lane & 15, q = lane >> 4;
    int rowBase = blockIdx.y * 64, colBase = blockIdx.x * 128;
    f32x4 acc[8];
    #pragma unroll
    for (int ct = 0; ct < 8; ct++) acc[ct] = (f32x4){0.f, 0.f, 0.f, 0.f};

    for (int kk = 0; kk < K; kk += 32) {
        // ---- stage A: 64 rows x 32 k -> f16 LDS (2 chunks of 4 / thread)
        #pragma unroll
        for (int u = 0; u < 2; u++) {
            int f = tid + 256 * u;
            int r = f >> 3;
            int k4 = (f & 7) * 4;
            int row = rowBase + r;
            f16x4 h = (f16x4){(f16)0, (f16)0, (f16)0, (f16)0};
            if (row < M) {
                if constexpr (std::is_same_v<TA, float>) {
                    float4 v = *(const float4*)(A + (size_t)row * K + kk + k4);
                    h[0] = (f16)v.x; h[1] = (f16)v.y; h[2] = (f16)v.z; h[3] = (f16)v.w;
                } else {
                    h = *(const f16x4*)(A + (size_t)row * K + kk + k4);
                }
            }
            *(f16x4*)&Af[r][k4] = h;
        }
        // ---- stage B: 128 rows x 32 k f16 (2 f16x8 / thread)
        {
            int n = tid >> 1, hf = (tid & 1) * 16;
            size_t goff = (size_t)(colBase + n) * K + kk + hf;
            *(f16x8*)&Bf[n][hf]     = *(const f16x8*)(Bt + goff);
            *(f16x8*)&Bf[n][hf + 8] = *(const f16x8*)(Bt + goff + 8);
        }
        __syncthreads();
        f16x8 a = *(const f16x8*)&Af[w * 16 + m][q * 8];
        #pragma unroll
        for (int ct = 0; ct < 8; ct++) {
            f16x8 b = *(const f16x8*)&Bf[ct * 16 + m][q * 8];
            acc[ct] = __builtin_amdgcn_mfma_f32_16x16x32_f16(a, b, acc[ct], 0, 0, 0);
        }
        __syncthreads();
    }
    f16* ob = (colBase < HC) ? xlb : xrb;
    int obase = (colBase < HC) ? colBase : colBase - HC;
    #pragma unroll
    for (int ct = 0; ct < 8; ct++) {
        int col = colBase + ct * 16 + m;
        int ocol = obase + ct * 16 + m;
        float bb = bias[col];
        #pragma unroll
        for (int r = 0; r < 4; r++) {
            int row = rowBase + w * 16 + q * 4 + r;
            if (row < M) ob[(size_t)row * HC + ocol] = (f16)(acc[ct][r] + bb);
        }
    }
}

// ---------------------------------------------------------------------------
// Head GEMM (64x64, f16 single-term) with fused LayerNorm epilogue.
// ---------------------------------------------------------------------------
__global__ __launch_bounds__(256, 2)
void gemm_head(const f16* __restrict__ A, const f16* __restrict__ Bt,
               const float* __restrict__ bias,
               float* __restrict__ C, int M, int K,
               const float* __restrict__ ln_g, const float* __restrict__ ln_b) {
    __shared__ _Float16 Af[64][LDT];
    __shared__ _Float16 Bf[64][LDT];
    int tid = threadIdx.x;
    int lane = tid & 63, w = tid >> 6;
    int m = lane & 15, q = lane >> 4;
    int rowBase = blockIdx.y * 64;
    f32x4 acc[4];
    #pragma unroll
    for (int ct = 0; ct < 4; ct++) acc[ct] = (f32x4){0.f, 0.f, 0.f, 0.f};

    for (int kk = 0; kk < K; kk += 32) {
        #pragma unroll
        for (int u = 0; u < 2; u++) {
            int f = tid + 256 * u;
            int r = f >> 3;
            int k4 = (f & 7) * 4;
            int row = rowBase + r;
            f16x4 h = (f16x4){(f16)0, (f16)0, (f16)0, (f16)0};
            if (row < M) h = *(const f16x4*)(A + (size_t)row * K + kk + k4);
            *(f16x4*)&Af[r][k4] = h;
        }
        {
            int n = tid >> 2;
            int ch = tid & 3;
            size_t goff = (size_t)n * K + kk + ch * 8;
            *(f16x8*)&Bf[n][ch * 8] = *(const f16x8*)(Bt + goff);
        }
        __syncthreads();
        f16x8 a = *(const f16x8*)&Af[w * 16 + m][q * 8];
        #pragma unroll
        for (int ct = 0; ct < 4; ct++) {
            f16x8 b = *(const f16x8*)&Bf[ct * 16 + m][q * 8];
            acc[ct] = __builtin_amdgcn_mfma_f32_16x16x32_f16(a, b, acc[ct], 0, 0, 0);
        }
        __syncthreads();
    }
    // LN epilogue: row held by 16 lanes (m) x 4 cols (ct)
    #pragma unroll
    for (int r = 0; r < 4; r++) {
        float v[4];
        float sum = 0.f;
        #pragma unroll
        for (int ct = 0; ct < 4; ct++) {
            v[ct] = acc[ct][r] + bias[ct * 16 + m];
            sum += v[ct];
        }
        sum += __shfl_xor(sum, 1); sum += __shfl_xor(sum, 2);
        sum += __shfl_xor(sum, 4); sum += __shfl_xor(sum, 8);
        float mu = sum * (1.f / 64.f);
        float sq = 0.f;
        #pragma unroll
        for (int ct = 0; ct < 4; ct++) {
            float d = v[ct] - mu;
            sq += d * d;
        }
        sq += __shfl_xor(sq, 1); sq += __shfl_xor(sq, 2);
        sq += __shfl_xor(sq, 4); sq += __shfl_xor(sq, 8);
        float inv = rsqrtf(sq * (1.f / 64.f) + LN_EPS);
        int row = rowBase + w * 16 + q * 4 + r;
        if (row < M) {
            #pragma unroll
            for (int ct = 0; ct < 4; ct++) {
                int col = ct * 16 + m;
                C[(size_t)row * 64 + col] = (v[ct] - mu) * inv * ln_g[col] + ln_b[col];
            }
        }
    }
}

// ---------------------------------------------------------------------------
// score_kernel (persistent): per 64-slot group, ee = ea @ We via single f16
// MFMA, fused GATv2 score epilogue in packed f16 (R10 known-good form).
// Lane m owns channels [m*16 .. m*16+15].
// ---------------------------------------------------------------------------
__global__ __launch_bounds__(256, 2)
void score_kernel(const f16* __restrict__ efp,
                  const int* __restrict__ srcf, const int* __restrict__ dstf,
                  const f16* __restrict__ xlb, const f16* __restrict__ xrb,
                  const f16* __restrict__ wet,
                  const float* __restrict__ att, float* __restrict__ alpha) {
    __shared__ _Float16 Af[64][LDT];
    __shared__ _Float16 Bf[256][LDT];
    __shared__ int s_src[64], s_dst[64];
    int tid = threadIdx.x;
    int lane = tid & 63, w = tid >> 6;
    int m = lane & 15, q = lane >> 4;

    // stage B (We^T permuted f16, [256][32]) ONCE
    #pragma unroll
    for (int u = 0; u < 4; u++) {
        *(f16x8*)&Bf[tid][u * 8] = *(const f16x8*)(wet + (size_t)tid * EDIM + u * 8);
    }
    // att coefficients of channels m*16..m*16+15 as packed f16
    f16x8 attp0, attp1;
    #pragma unroll
    for (int i = 0; i < 8; i++) {
        attp0[i] = (f16)att[m * 16 + i];
        attp1[i] = (f16)att[m * 16 + 8 + i];
    }

    const f16x8 zero8 = {(f16)0, (f16)0, (f16)0, (f16)0, (f16)0, (f16)0, (f16)0, (f16)0};

    int groups = (EESLOTS + 63) >> 6;
    for (int g = blockIdx.x; g < groups; g += gridDim.x) {
        int base = g << 6;
        __syncthreads();   // protect Af + s_src reads of previous group
        // stage A: 64 slots x 32 k, sequential f16 stream from efp
        {
            int r = tid >> 2, ch = tid & 3;
            int j = base + r;
            if (j >= EESLOTS) j = EESLOTS - 1;
            *(f16x8*)&Af[r][ch * 8] = *(const f16x8*)(efp + (size_t)j * EDIM + ch * 8);
            if (ch == 0) { s_src[r] = srcf[j]; s_dst[r] = dstf[j]; }
        }
        __syncthreads();

        f16x8 a = *(const f16x8*)&Af[w * 16 + m][q * 8];
        f32x4 acc[16];
        #pragma unroll
        for (int ct = 0; ct < 16; ct++) {
            f16x8 b = *(const f16x8*)&Bf[ct * 16 + m][q * 8];
            acc[ct] = __builtin_amdgcn_mfma_f32_16x16x32_f16(
                a, b, (f32x4){0.f, 0.f, 0.f, 0.f}, 0, 0, 0);
        }

        // epilogue: per-slot score (packed f16 math)
        #pragma unroll
        for (int r = 0; r < 4; r++) {
            int sl = w * 16 + q * 4 + r;
            int slot = base + sl;
            int ss = s_src[sl], dd = s_dst[sl];
            const f16* xlp = xlb + (size_t)ss * HC + m * 16;
            const f16* xrp = xrb + (size_t)dd * HC + m * 16;
            f16x8 xa0 = *(const f16x8*)(xlp);
            f16x8 xa1 = *(const f16x8*)(xlp + 8);
            f16x8 xb0 = *(const f16x8*)(xrp);
            f16x8 xb1 = *(const f16x8*)(xrp + 8);
            f16x8 z0 = xa0 + xb0;
            f16x8 z1 = xa1 + xb1;
            f16x8 e0, e1;
            #pragma unroll
            for (int i = 0; i < 8; i++) {
                e0[i] = (f16)acc[i][r];
                e1[i] = (f16)acc[8 + i][r];
            }
            z0 += e0;
            z1 += e1;
            f16x8 lz0 = __builtin_elementwise_min(z0, zero8) * (f16)0.2f
                      + __builtin_elementwise_max(z0, zero8);
            f16x8 lz1 = __builtin_elementwise_min(z1, zero8) * (f16)0.2f
                      + __builtin_elementwise_max(z1, zero8);
            float s0 = 0.f, s1 = 0.f;
#if __has_builtin(__builtin_amdgcn_fdot2)
            #pragma unroll
            for (int i = 0; i < 4; i++) {
                f16x2 a2 = {lz0[2 * i], lz0[2 * i + 1]};
                f16x2 b2 = {attp0[2 * i], attp0[2 * i + 1]};
                s0 = __builtin_amdgcn_fdot2(a2, b2, s0, false);
                f16x2 c2 = {lz1[2 * i], lz1[2 * i + 1]};
                f16x2 d2 = {attp1[2 * i], attp1[2 * i + 1]};
                s1 = __builtin_amdgcn_fdot2(c2, d2, s1, false);
            }
#else
            #pragma unroll
            for (int i = 0; i < 8; i++) {
                s0 += (float)lz0[i] * (float)attp0[i];
                s1 += (float)lz1[i] * (float)attp1[i];
            }
#endif
            float s = s0 + s1;
            // head h = m>>2: reduce over the 4 lanes m in [4h..4h+3]
            s += __shfl_xor(s, 1);
            s += __shfl_xor(s, 2);
            if ((m & 3) == 0 && slot < EESLOTS) {
                alpha[(size_t)slot * 4 + (m >> 2)] = s;
            }
        }
    }
}

// ---------------------------------------------------------------------------
// Lean aggregation: softmax over precomputed alpha (shift = alpha_self),
// weighted gather of fp16 xl from xlb. One wave per node, ILP x8.
// Output xb in FP16.
// ---------------------------------------------------------------------------
__global__ __launch_bounds__(256)
void gat_aggr(const f16* __restrict__ xlb, const float* __restrict__ alpha,
              const int* __restrict__ row_ptr, const int* __restrict__ srcf,
              const float* __restrict__ bias, f16* __restrict__ out, int do_relu) {
    int lane = threadIdx.x & 63;
    int wv = threadIdx.x >> 6;
    int n = blockIdx.x * 4 + wv;
    if (n >= NN) return;
    int h = lane >> 4;
    float4 bb = *(const float4*)(bias + 4 * lane);
    int s0 = row_ptr[n], e0 = row_ptr[n + 1];
    float aself = alpha[(size_t)(NE + n) * 4 + h];
    float denom = 1.f;
    f16x4 xs = *(const f16x4*)(xlb + (size_t)n * HC + 4 * lane);
    float4 acc = make_float4((float)xs[0], (float)xs[1], (float)xs[2], (float)xs[3]);

    for (int j0 = s0; j0 < e0; j0 += 64) {
        int cnt = min(64, e0 - j0);
        int sidx = (j0 + lane < e0) ? srcf[j0 + lane] : 0;
        int t = 0;
        for (; t + 7 < cnt; t += 8) {
            int si[8];
            #pragma unroll
            for (int u = 0; u < 8; u++) si[u] = __shfl(sidx, t + u);
            float av[8];
            #pragma unroll
            for (int u = 0; u < 8; u++)
                av[u] = __expf(alpha[(size_t)(j0 + t + u) * 4 + h] - aself);
            f16x4 xv[8];
            #pragma unroll
            for (int u = 0; u < 8; u++)
                xv[u] = *(const f16x4*)(xlb + (size_t)si[u] * HC + 4 * lane);
            #pragma unroll
            for (int u = 0; u < 8; u++) {
                denom += av[u];
                acc.x += av[u] * (float)xv[u][0];
                acc.y += av[u] * (float)xv[u][1];
                acc.z += av[u] * (float)xv[u][2];
                acc.w += av[u] * (float)xv[u][3];
            }
        }
        for (; t < cnt; t++) {
            int sa = __shfl(sidx, t);
            float a0 = __expf(alpha[(size_t)(j0 + t) * 4 + h] - aself);
            f16x4 x0 = *(const f16x4*)(xlb + (size_t)sa * HC + 4 * lane);
            denom += a0;
            acc.x += a0 * (float)x0[0]; acc.y += a0 * (float)x0[1];
            acc.z += a0 * (float)x0[2]; acc.w += a0 * (float)x0[3];
        }
    }

    float inv = 1.f / denom;
    float rx = acc.x * inv + bb.x;
    float ry = acc.y * inv + bb.y;
    float rz = acc.z * inv + bb.z;
    float rw = acc.w * inv + bb.w;
    if (do_relu) {
        rx = fmaxf(rx, 0.f); ry = fmaxf(ry, 0.f);
        rz = fmaxf(rz, 0.f); rw = fmaxf(rw, 0.f);
    }
    f16x4 o;
    o[0] = (f16)rx; o[1] = (f16)ry; o[2] = (f16)rz; o[3] = (f16)rw;
    *(f16x4*)(out + (size_t)n * HC + 4 * lane) = o;
}

// ---------------------------------------------------------------------------
// Graph mean pre-reduction exploiting sorted batch. 64 rows/block, f16 input.
// ---------------------------------------------------------------------------
__global__ void graph_sum(const f16* __restrict__ x, const int* __restrict__ batch,
                          float* __restrict__ gsum, float* __restrict__ gcnt) {
    int c = threadIdx.x;
    int r0 = blockIdx.x * 64;
    int r1 = min(r0 + 64, NN);
    if (r0 >= NN) return;
    float acc = 0.f;
    int gcur = batch[r0];
    for (int n = r0; n < r1; n++) {
        int g = batch[n];
        if (g != gcur) {
            atomicAdd(&gsum[(size_t)gcur * HC + c], acc);
            acc = 0.f; gcur = g;
        }
        acc += (float)x[(size_t)n * HC + c];
    }
    atomicAdd(&gsum[(size_t)gcur * HC + c], acc);
    if (c == 0) {
        int cnt = 0; gcur = batch[r0];
        for (int n = r0; n < r1; n++) {
            int g = batch[n];
            if (g != gcur) {
                atomicAdd(&gcnt[gcur], (float)cnt);
                cnt = 0; gcur = g;
            }
            cnt++;
        }
        atomicAdd(&gcnt[gcur], (float)cnt);
    }
}

__global__ void glob_kernel(const float* __restrict__ gsum, const float* __restrict__ gcnt,
                            const float* __restrict__ W, const float* __restrict__ bias,
                            const float* __restrict__ g, const float* __restrict__ b,
                            float* __restrict__ out) {
    int gi = blockIdx.x;
    int lane = threadIdx.x;
    float inv = 1.f / fmaxf(gcnt[gi], 1.f);
    float acc = 0.f;
    for (int k = 0; k < HC; k++)
        acc += (gsum[(size_t)gi * HC + k] * inv) * W[(size_t)k * ND + lane];
    acc += bias[lane];
    float s = acc;
    #pragma unroll
    for (int o = 32; o >= 1; o >>= 1) s += __shfl_xor(s, o);
    float mu = s * (1.f / 64.f);
    float dv = acc - mu;
    float q = dv * dv;
    #pragma unroll
    for (int o = 32; o >= 1; o >>= 1) q += __shfl_xor(q, o);
    float var = q * (1.f / 64.f);
    out[(size_t)gi * ND + lane] = dv * rsqrtf(var + LN_EPS) * g[lane] + b[lane];
}

// ---------------------------------------------------------------------------
extern "C" void kernel_launch(void* const* d_in, const int* in_sizes, int n_in,
                              void* d_out, int out_size, void* d_ws, size_t ws_size,
                              hipStream_t stream) {
    (void)in_sizes; (void)n_in; (void)out_size; (void)ws_size;
    const float* node_feature = (const float*)d_in[0];
    const int*   edge_index   = (const int*)d_in[1];
    const float* edge_feature = (const float*)d_in[2];
    const int*   batch        = (const int*)d_in[3];
    const float* Wl0   = (const float*)d_in[4];
    const float* bl0   = (const float*)d_in[5];
    const float* Wr0   = (const float*)d_in[6];
    const float* br0   = (const float*)d_in[7];
    const float* We0   = (const float*)d_in[8];
    const float* att0  = (const float*)d_in[9];
    const float* bias0 = (const float*)d_in[10];
    const float* Wl1   = (const float*)d_in[11];
    const float* bl1   = (const float*)d_in[12];
    const float* Wr1   = (const float*)d_in[13];
    const float* br1   = (const float*)d_in[14];
    const float* We1   = (const float*)d_in[15];
    const float* att1  = (const float*)d_in[16];
    const float* bias1 = (const float*)d_in[17];
    const float* node_W  = (const float*)d_in[18];
    const float* node_b  = (const float*)d_in[19];
    const float* graph_W = (const float*)d_in[20];
    const float* graph_b = (const float*)d_in[21];
    const float* nn_g = (const float*)d_in[22];
    const float* nn_b = (const float*)d_in[23];
    const float* gn_g = (const float*)d_in[24];
    const float* gn_b = (const float*)d_in[25];

    const int* src = edge_index;
    const int* dst = edge_index + NE;

    char* p = (char*)d_ws;
    auto carve = [&](size_t bytes) {
        char* r = p;
        p += (bytes + 255) & ~(size_t)255;
        return r;
    };
    int*   row_ptr   = (int*)carve((NN + 1) * sizeof(int));
    int*   cursor    = (int*)carve(NN * sizeof(int));
    int*   deg       = (int*)carve(NN * sizeof(int));
    int*   bsum      = (int*)carve(SCAN_B * sizeof(int));
    int*   boff      = (int*)carve(SCAN_B * sizeof(int));
    int*   csr_eid   = (int*)carve((size_t)NE * sizeof(int));
    int*   srcf      = (int*)carve((size_t)EESLOTS * sizeof(int));
    int*   dstf      = (int*)carve((size_t)EESLOTS * sizeof(int));
    f16*   efp       = (f16*)carve((size_t)EESLOTS * EDIM * sizeof(f16));
    f16*   xlb       = (f16*)carve((size_t)NN * HC * sizeof(f16));   // xl fp16
    f16*   xrb       = (f16*)carve((size_t)NN * HC * sizeof(f16));   // xr fp16
    f16*   xb        = (f16*)carve((size_t)NN * HC * sizeof(f16));   // fp16 node state
    float* alpha     = (float*)carve((size_t)EESLOTS * NH * sizeof(float));
    float* gsum      = (float*)carve((size_t)(NGG * HC + NGG) * sizeof(float));
    float* gcnt      = gsum + (size_t)NGG * HC;
    // layer GEMM weights: f16 transposed [512][K]
    f16* wlr0f = (f16*)carve((size_t)(2 * HC) * DIN * sizeof(f16));
    f16* wlr1f = (f16*)carve((size_t)(2 * HC) * HC * sizeof(f16));
    // head weights: f16 transposed [ND][HC]
    f16* nwf = (f16*)carve((size_t)ND * HC * sizeof(f16));
    f16* wet0 = (f16*)carve((size_t)EDIM * HC * sizeof(f16));
    f16* wet1 = (f16*)carve((size_t)EDIM * HC * sizeof(f16));
    float* b0cat = (float*)carve(2 * HC * sizeof(float));
    float* b1cat = (float*)carve(2 * HC * sizeof(float));

    hipMemsetAsync(deg, 0, NN * sizeof(int), stream);
    hipMemsetAsync(gsum, 0, (NGG * HC + NGG) * sizeof(float), stream);

    // CSR (3-kernel scan) + efp pre-permutation + weight conversion
    count_deg<<<(NE + 255) / 256, 256, 0, stream>>>(dst, deg);
    scan_bsum<<<SCAN_NB, SCAN_B, 0, stream>>>(deg, bsum);
    scan_boff<<<1, SCAN_B, 0, stream>>>(bsum, boff);
    scan_final<<<SCAN_NB, SCAN_B, 0, stream>>>(deg, boff, row_ptr, cursor);
    fill_csr<<<(NE + 255) / 256, 256, 0, stream>>>(src, dst, cursor, srcf, dstf, csr_eid);
    perm_ef<<<(NE * 4 + 255) / 256, 256, 0, stream>>>(edge_feature, csr_eid, efp);
    self_slots<<<(NN * EDIM + 255) / 256, 256, 0, stream>>>(row_ptr, efp, srcf, dstf);
    conv_wtf<<<(DIN * HC + 255) / 256, 256, 0, stream>>>(Wl0, wlr0f, DIN, HC);
    conv_wtf<<<(DIN * HC + 255) / 256, 256, 0, stream>>>(Wr0, wlr0f + (size_t)HC * DIN, DIN, HC);
    conv_wtf<<<(HC * HC + 255) / 256, 256, 0, stream>>>(Wl1, wlr1f, HC, HC);
    conv_wtf<<<(HC * HC + 255) / 256, 256, 0, stream>>>(Wr1, wlr1f + (size_t)HC * HC, HC, HC);
    conv_wtf<<<(HC * ND + 255) / 256, 256, 0, stream>>>(node_W, nwf, HC, ND);
    conv_wet<<<(EDIM * HC + 255) / 256, 256, 0, stream>>>(We0, wet0);
    conv_wet<<<(EDIM * HC + 255) / 256, 256, 0, stream>>>(We1, wet1);
    concat_bias<<<1, 256, 0, stream>>>(bl0, br0, b0cat);
    concat_bias<<<1, 256, 0, stream>>>(bl1, br1, b1cat);

    dim3 gw(4, (NN + 63) / 64);
    // Layer 0
    gemm_wide<float><<<gw, 256, 0, stream>>>(node_feature, wlr0f, b0cat, xlb, xrb, NN, DIN);
    score_kernel<<<2048, 256, 0, stream>>>(efp, srcf, dstf, xlb, xrb, wet0, att0, alpha);
    gat_aggr<<<(NN + 3) / 4, 256, 0, stream>>>(xlb, alpha, row_ptr, srcf, bias0, xb, 1);
    // Layer 1
    gemm_wide<f16><<<gw, 256, 0, stream>>>(xb, wlr1f, b1cat, xlb, xrb, NN, HC);
    score_kernel<<<2048, 256, 0, stream>>>(efp, srcf, dstf, xlb, xrb, wet1, att1, alpha);
    gat_aggr<<<(NN + 3) / 4, 256, 0, stream>>>(xlb, alpha, row_ptr, srcf, bias1, xb, 0);

    // Heads
    float* out_local = (float*)d_out;
    float* out_glob  = out_local + (size_t)NN * ND;
    dim3 gh(1, (NN + 63) / 64);
    gemm_head<<<gh, 256, 0, stream>>>(xb, nwf, node_b, out_local, NN, HC, nn_g, nn_b);
    graph_sum<<<(NN + 63) / 64, 256, 0, stream>>>(xb, batch, gsum, gcnt);
    glob_kernel<<<NGG, 64, 0, stream>>>(gsum, gcnt, graph_W, graph_b, gn_g, gn_b, out_glob);
}